// Round 3
// baseline (253.912 us; speedup 1.0000x reference)
//
#include <hip/hip_runtime.h>
#include <hip/hip_cooperative_groups.h>

namespace cg = cooperative_groups;

// Problem constants (B,L,H,E,M) = (4,4096,8,64,64)
#define Bsz 4
#define Lsz 4096
#define HEsz 512      // H*E rows per batch
#define SPLIT 16      // split-K for the forward DFT

typedef __attribute__((ext_vector_type(8))) short short8;
typedef __attribute__((ext_vector_type(4))) float f32x4;

// workspace byte offsets (total ~9 MiB; ws is 256 MiB)
#define OFF_CF  0u        // ushort[2048][128] mixed coeffs bf16 (512 KB)
#define OFF_C1P (1u<<20)  // ushort[SPLIT][4][512][128] split-K partials bf16 (8 MB)

static __device__ __forceinline__ unsigned short f2bf(float f) {
    union { float f; unsigned u; } v; v.f = f;
    unsigned u = v.u;
    return (unsigned short)((u + 0x7fffu + ((u >> 16) & 1u)) >> 16);   // RNE
}
static __device__ __forceinline__ unsigned pk2(float a, float b) {
    return (unsigned)f2bf(a) | ((unsigned)f2bf(b) << 16);
}
static __device__ __forceinline__ float bf2f(unsigned short u) {
    union { unsigned u; float f; } v; v.u = ((unsigned)u) << 16;
    return v.f;
}
static __device__ __forceinline__ void sc(int m, int l, float* s, float* c) {
    int r = (m * l) & (Lsz - 1);                       // exact mod, L = 4096
    float ang = (float)r * (6.283185307179586f / (float)Lsz);
    __sincosf(ang, s, c);
}

// =====================================================================
// Fused cooperative kernel: phase1 dft -> sync -> phase2 mix -> sync -> phase3 idft
// 512 blocks x 256 threads, 2 blocks/CU, 64 KB LDS/block.
// Phase-3 basis (basI) is generated during phase 1 (no dependencies), so
// phase 3 starts MFMA as soon as Cf lands.
// =====================================================================
__global__ __launch_bounds__(256, 2) void k_fused(const float* __restrict__ q,
                                                  const float* __restrict__ wr,
                                                  const float* __restrict__ wi,
                                                  unsigned short* __restrict__ C1P,
                                                  unsigned short* __restrict__ Cf,
                                                  float* __restrict__ out) {
    __shared__ unsigned short LDS[32768];     // 64 KB
    unsigned short* As1 = LDS;                // phase1 A  [64*64]   (8 KB)
    unsigned short* Bs1 = LDS + 4096;         // phase1 B  [128*64]  (16 KB); epilogue [64][128]
    unsigned short* BI  = LDS + 16384;        // phase3 basis [128*128] (32 KB, persists ph1->ph3)

    const int bid = blockIdx.x;
    const int t = threadIdx.x, lane = t & 63, w = t >> 6;
    const int quad = lane >> 4, lid = lane & 15;

    // ---------------- phase 1: forward truncated DFT, split-K bf16 partials ----
    {
        const int ks = bid & 15, ht = (bid >> 4) & 7, b = bid >> 7;
        const int he0 = ht * 64;
        const int wtm = w & 1, wtn = w >> 1;  // wave tile: 32he x 64c
        f32x4 acc[2][4] = {};

        const int kbeg = ks * (Lsz / SPLIT);
        const float* qp0 = q + ((size_t)(b * Lsz + kbeg + w * 16) * HEsz + he0 + lane);

        float f[16], f2[16];
#pragma unroll
        for (int j = 0; j < 16; ++j) f[j] = qp0[(size_t)j * HEsz];   // prologue: ch 0

#pragma unroll
        for (int ch = 0; ch < 4; ++ch) {
            // A: pack the already-loaded q slice
            {
                uint4 p0 = make_uint4(pk2(f[0], f[1]), pk2(f[2], f[3]), pk2(f[4], f[5]), pk2(f[6], f[7]));
                uint4 p1 = make_uint4(pk2(f[8], f[9]), pk2(f[10], f[11]), pk2(f[12], f[13]), pk2(f[14], f[15]));
                int row = lane;
                int cb0 = (w * 2) ^ (row & 7), cb1 = (w * 2 + 1) ^ (row & 7);
                *(uint4*)(As1 + row * 64 + cb0 * 8) = p0;
                *(uint4*)(As1 + row * 64 + cb1 * 8) = p1;
            }
            // prefetch ch+1 q into registers
            if (ch < 3) {
                const float* qp = qp0 + (size_t)(ch + 1) * 64 * HEsz;
#pragma unroll
                for (int j = 0; j < 16; ++j) f2[j] = qp[(size_t)j * HEsz];
            }
            // B: generate basF tile in-register. thread -> m = t&63, 16 l's.
            {
                int m = t & 63, lg = t >> 6;
                int c0 = 2 * m, c1 = 2 * m + 1;
                const int l0 = kbeg + ch * 64;
#pragma unroll
                for (int h = 0; h < 2; ++h) {
                    float sv[8], cv[8];
#pragma unroll
                    for (int j = 0; j < 8; ++j)
                        sc(m, l0 + lg * 16 + h * 8 + j, &sv[j], &cv[j]);
                    uint4 pc = make_uint4(pk2(cv[0], cv[1]), pk2(cv[2], cv[3]),
                                          pk2(cv[4], cv[5]), pk2(cv[6], cv[7]));
                    uint4 ps = make_uint4(pk2(-sv[0], -sv[1]), pk2(-sv[2], -sv[3]),
                                          pk2(-sv[4], -sv[5]), pk2(-sv[6], -sv[7]));
                    int lb = lg * 2 + h;
                    *(uint4*)(Bs1 + c0 * 64 + ((lb ^ (c0 & 7)) * 8)) = pc;
                    *(uint4*)(Bs1 + c1 * 64 + ((lb ^ (c1 & 7)) * 8)) = ps;
                }
            }
            __syncthreads();
#pragma unroll
            for (int kst = 0; kst < 2; ++kst) {
                short8 af[2], bfr[4];
#pragma unroll
                for (int mt = 0; mt < 2; ++mt) {
                    int m = wtm * 32 + mt * 16 + lid;
                    int cb = (kst * 4 + quad) ^ (m & 7);
                    af[mt] = *(short8*)(As1 + m * 64 + cb * 8);
                }
#pragma unroll
                for (int nt = 0; nt < 4; ++nt) {
                    int n = wtn * 64 + nt * 16 + lid;
                    int cb = (kst * 4 + quad) ^ (n & 7);
                    bfr[nt] = *(short8*)(Bs1 + n * 64 + cb * 8);
                }
#pragma unroll
                for (int mt = 0; mt < 2; ++mt)
#pragma unroll
                    for (int nt = 0; nt < 4; ++nt)
                        acc[mt][nt] = __builtin_amdgcn_mfma_f32_16x16x32_bf16(af[mt], bfr[nt], acc[mt][nt], 0, 0, 0);
            }
            __syncthreads();
            if (ch < 3) {
#pragma unroll
                for (int j = 0; j < 16; ++j) f[j] = f2[j];
            }
        }
        // epilogue: restage bf16 into Bs1 as [64][128] (swizzled), coalesced uint4 stores
#pragma unroll
        for (int mt = 0; mt < 2; ++mt)
#pragma unroll
            for (int nt = 0; nt < 4; ++nt) {
                int col = wtn * 64 + nt * 16 + lid;
#pragma unroll
                for (int r = 0; r < 4; ++r) {
                    int row = wtm * 32 + mt * 16 + quad * 4 + r;
                    int cb = (col >> 3) ^ (row & 15);
                    Bs1[row * 128 + cb * 8 + (col & 7)] = f2bf(acc[mt][nt][r]);
                }
            }
        __syncthreads();
        unsigned short* dst = C1P + (((size_t)ks * Bsz + b) * HEsz + he0) * 128;
#pragma unroll
        for (int it = 0; it < 4; ++it) {
            int slot = t + it * 256;
            int r = slot >> 4, cb = slot & 15;
            *(uint4*)(dst + (size_t)r * 128 + cb * 8) =
                *(const uint4*)(Bs1 + r * 128 + ((cb ^ (r & 15)) * 8));
        }
    }

    // ---------------- phase-3 basis gen (independent; overlaps C1P stores) ----
    {
        const int lt = bid & 31;
        int lr = t >> 1, half = t & 1;
        int lg = lt * 128 + lr;
#pragma unroll
        for (int jj = 0; jj < 8; ++jj) {
            unsigned wv[4];
#pragma unroll
            for (int j = 0; j < 4; ++j) {
                int m = half * 32 + jj * 4 + j;
                float s, co; sc(m, lg, &s, &co);
                float wm = (m == 0) ? (1.0f / Lsz) : (2.0f / Lsz);
                wv[j] = pk2(wm * co, wm * s);
            }
            int cb = half * 8 + jj;
            *(uint4*)(BI + lr * 128 + ((cb ^ (lr & 15)) * 8)) =
                make_uint4(wv[0], wv[1], wv[2], wv[3]);
        }
    }

    cg::this_grid().sync();

    // ---------------- phase 2: split-K reduce + head mixing (blocks 0..255) ----
    if (bid < 256) {
        float* X = (float*)LDS;               // [8][128], 4 KB (As1/Bs1 dead; BI untouched)
        const int e = bid & 63, b = bid >> 6;
        const int i = t >> 5, c4 = t & 31;
        size_t off = ((size_t)b * HEsz + i * 64 + e) * 128 + c4 * 4;
        float sx = 0.f, sy = 0.f, sz = 0.f, sw = 0.f;
#pragma unroll
        for (int sp = 0; sp < SPLIT; ++sp) {
            uint2 v = *(const uint2*)(C1P + off + (size_t)sp * (Bsz * HEsz * 128));
            sx += bf2f((unsigned short)(v.x & 0xffff));
            sy += bf2f((unsigned short)(v.x >> 16));
            sz += bf2f((unsigned short)(v.y & 0xffff));
            sw += bf2f((unsigned short)(v.y >> 16));
        }
        *(float4*)&X[(size_t)i * 128 + c4 * 4] = make_float4(sx, sy, sz, sw);
        __syncthreads();
#pragma unroll
        for (int it = 0; it < 2; ++it) {
            int item = t + it * 256;
            int o = item >> 6, m = item & 63;
            float ar = 0.f, ai = 0.f;
#pragma unroll
            for (int i2 = 0; i2 < 8; ++i2) {
                float xr = X[(size_t)i2 * 128 + 2 * m], xi = X[(size_t)i2 * 128 + 2 * m + 1];
                size_t wo = ((size_t)(i2 * 8 + o) * 64 + e) * 64 + m;
                float wrv = wr[wo], wiv = wi[wo];
                ar += xr * wrv - xi * wiv;
                ai += xr * wiv + xi * wrv;
            }
            int row = b * HEsz + o * 64 + e;
            *(unsigned*)(Cf + (size_t)row * 128 + 2 * m) = pk2(ar, -ai);
        }
    }

    cg::this_grid().sync();

    // ---------------- phase 3: truncated irfft (basis already in BI) ----------
    {
        const int lt = bid & 31, rt = bid >> 5;
        const int l0 = lt * 128, row0 = rt * 128;
        const int wtm = w & 1, wtn = w >> 1;  // wave tile 64 x 64
        unsigned short* As3 = LDS;            // [128*128] swz16 (32 KB)

        // stage Cf rows into LDS (issue loads, then write)
        uint4 a[8];
#pragma unroll
        for (int it = 0; it < 8; ++it) {
            int slot = t + it * 256;
            int r = slot >> 4, cb = slot & 15;
            a[it] = *(const uint4*)(Cf + (size_t)(row0 + r) * 128 + cb * 8);
        }
#pragma unroll
        for (int it = 0; it < 8; ++it) {
            int slot = t + it * 256;
            int r = slot >> 4, cb = slot & 15;
            *(uint4*)(As3 + r * 128 + ((cb ^ (r & 15)) * 8)) = a[it];
        }
        __syncthreads();
        f32x4 acc[4][4] = {};
#pragma unroll
        for (int kst = 0; kst < 4; ++kst) {
            short8 af[4], bfr[4];
#pragma unroll
            for (int mt = 0; mt < 4; ++mt) {
                int m = wtm * 64 + mt * 16 + lid;
                int cb = (kst * 4 + quad) ^ (m & 15);
                af[mt] = *(short8*)(As3 + m * 128 + cb * 8);
            }
#pragma unroll
            for (int nt = 0; nt < 4; ++nt) {
                int n = wtn * 64 + nt * 16 + lid;
                int cb = (kst * 4 + quad) ^ (n & 15);
                bfr[nt] = *(short8*)(BI + n * 128 + cb * 8);
            }
#pragma unroll
            for (int mt = 0; mt < 4; ++mt)
#pragma unroll
                for (int nt = 0; nt < 4; ++nt)
                    acc[mt][nt] = __builtin_amdgcn_mfma_f32_16x16x32_bf16(af[mt], bfr[nt], acc[mt][nt], 0, 0, 0);
        }
        __syncthreads();
        // transpose through LDS (full 64 KB as float[128][128], swizzled writes)
        float* outb = (float*)LDS;
#pragma unroll
        for (int mt = 0; mt < 4; ++mt)
#pragma unroll
            for (int nt = 0; nt < 4; ++nt) {
                int col = wtn * 64 + nt * 16 + lid;
                int c4 = col >> 2, cr = col & 3;
#pragma unroll
                for (int r = 0; r < 4; ++r) {
                    int row = wtm * 64 + mt * 16 + quad * 4 + r;
                    outb[(size_t)row * 128 + ((c4 ^ (row & 7)) << 2) + cr] = acc[mt][nt][r];
                }
            }
        __syncthreads();
#pragma unroll
        for (int it = 0; it < 16; ++it) {
            int slot = t + it * 256;
            int r = slot >> 5, c4 = slot & 31;
            float4 v = *(float4*)(outb + (size_t)r * 128 + ((c4 ^ (r & 7)) << 2));
            *(float4*)(out + (size_t)(row0 + r) * Lsz + l0 + c4 * 4) = v;
        }
    }
}

// =====================================================================
// Fallback path: the previous 3-kernel pipeline (used if cooperative
// launch is unavailable / occupancy check fails).
// =====================================================================
__global__ __launch_bounds__(256, 2) void k_dft(const float* __restrict__ q,
                                                unsigned short* __restrict__ C1P) {
    __shared__ unsigned short As[64 * 64];
    __shared__ unsigned short Bs[128 * 64];
    const int ks = blockIdx.x, ht = blockIdx.y, b = blockIdx.z;
    const int he0 = ht * 64;
    const int t = threadIdx.x, lane = t & 63, w = t >> 6;
    const int wtm = w & 1, wtn = w >> 1;
    const int quad = lane >> 4, lid = lane & 15;
    f32x4 acc[2][4] = {};
    const int kbeg = ks * (Lsz / SPLIT);
    const float* qp0 = q + ((size_t)(b * Lsz + kbeg + w * 16) * HEsz + he0 + lane);
    float f[16], f2[16];
#pragma unroll
    for (int j = 0; j < 16; ++j) f[j] = qp0[(size_t)j * HEsz];
#pragma unroll
    for (int ch = 0; ch < 4; ++ch) {
        {
            uint4 p0 = make_uint4(pk2(f[0], f[1]), pk2(f[2], f[3]), pk2(f[4], f[5]), pk2(f[6], f[7]));
            uint4 p1 = make_uint4(pk2(f[8], f[9]), pk2(f[10], f[11]), pk2(f[12], f[13]), pk2(f[14], f[15]));
            int row = lane;
            int cb0 = (w * 2) ^ (row & 7), cb1 = (w * 2 + 1) ^ (row & 7);
            *(uint4*)(As + row * 64 + cb0 * 8) = p0;
            *(uint4*)(As + row * 64 + cb1 * 8) = p1;
        }
        if (ch < 3) {
            const float* qp = qp0 + (size_t)(ch + 1) * 64 * HEsz;
#pragma unroll
            for (int j = 0; j < 16; ++j) f2[j] = qp[(size_t)j * HEsz];
        }
        {
            int m = t & 63, lg = t >> 6;
            int c0 = 2 * m, c1 = 2 * m + 1;
            const int l0 = kbeg + ch * 64;
#pragma unroll
            for (int h = 0; h < 2; ++h) {
                float sv[8], cv[8];
#pragma unroll
                for (int j = 0; j < 8; ++j)
                    sc(m, l0 + lg * 16 + h * 8 + j, &sv[j], &cv[j]);
                uint4 pc = make_uint4(pk2(cv[0], cv[1]), pk2(cv[2], cv[3]),
                                      pk2(cv[4], cv[5]), pk2(cv[6], cv[7]));
                uint4 ps = make_uint4(pk2(-sv[0], -sv[1]), pk2(-sv[2], -sv[3]),
                                      pk2(-sv[4], -sv[5]), pk2(-sv[6], -sv[7]));
                int lb = lg * 2 + h;
                *(uint4*)(Bs + c0 * 64 + ((lb ^ (c0 & 7)) * 8)) = pc;
                *(uint4*)(Bs + c1 * 64 + ((lb ^ (c1 & 7)) * 8)) = ps;
            }
        }
        __syncthreads();
#pragma unroll
        for (int kst = 0; kst < 2; ++kst) {
            short8 af[2], bfr[4];
#pragma unroll
            for (int mt = 0; mt < 2; ++mt) {
                int m = wtm * 32 + mt * 16 + lid;
                int cb = (kst * 4 + quad) ^ (m & 7);
                af[mt] = *(short8*)(As + m * 64 + cb * 8);
            }
#pragma unroll
            for (int nt = 0; nt < 4; ++nt) {
                int n = wtn * 64 + nt * 16 + lid;
                int cb = (kst * 4 + quad) ^ (n & 7);
                bfr[nt] = *(short8*)(Bs + n * 64 + cb * 8);
            }
#pragma unroll
            for (int mt = 0; mt < 2; ++mt)
#pragma unroll
                for (int nt = 0; nt < 4; ++nt)
                    acc[mt][nt] = __builtin_amdgcn_mfma_f32_16x16x32_bf16(af[mt], bfr[nt], acc[mt][nt], 0, 0, 0);
        }
        __syncthreads();
        if (ch < 3) {
#pragma unroll
            for (int j = 0; j < 16; ++j) f[j] = f2[j];
        }
    }
#pragma unroll
    for (int mt = 0; mt < 2; ++mt)
#pragma unroll
        for (int nt = 0; nt < 4; ++nt) {
            int col = wtn * 64 + nt * 16 + lid;
#pragma unroll
            for (int r = 0; r < 4; ++r) {
                int row = wtm * 32 + mt * 16 + quad * 4 + r;
                int cb = (col >> 3) ^ (row & 15);
                Bs[row * 128 + cb * 8 + (col & 7)] = f2bf(acc[mt][nt][r]);
            }
        }
    __syncthreads();
    unsigned short* dst = C1P + (((size_t)ks * Bsz + b) * HEsz + he0) * 128;
#pragma unroll
    for (int it = 0; it < 4; ++it) {
        int slot = t + it * 256;
        int r = slot >> 4, cb = slot & 15;
        *(uint4*)(dst + (size_t)r * 128 + cb * 8) =
            *(const uint4*)(Bs + r * 128 + ((cb ^ (r & 15)) * 8));
    }
}

__global__ __launch_bounds__(256) void k_mixreduce(const unsigned short* __restrict__ C1P,
                                                   const float* __restrict__ wr,
                                                   const float* __restrict__ wi,
                                                   unsigned short* __restrict__ Cf) {
    __shared__ float X[8][128];
    const int e = blockIdx.x & 63, b = blockIdx.x >> 6;
    const int t = threadIdx.x;
    const int i = t >> 5, c4 = t & 31;
    size_t off = ((size_t)b * HEsz + i * 64 + e) * 128 + c4 * 4;
    float sx = 0.f, sy = 0.f, sz = 0.f, sw = 0.f;
#pragma unroll
    for (int sp = 0; sp < SPLIT; ++sp) {
        uint2 v = *(const uint2*)(C1P + off + (size_t)sp * (Bsz * HEsz * 128));
        sx += bf2f((unsigned short)(v.x & 0xffff));
        sy += bf2f((unsigned short)(v.x >> 16));
        sz += bf2f((unsigned short)(v.y & 0xffff));
        sw += bf2f((unsigned short)(v.y >> 16));
    }
    *(float4*)&X[i][c4 * 4] = make_float4(sx, sy, sz, sw);
    __syncthreads();
#pragma unroll
    for (int it = 0; it < 2; ++it) {
        int item = t + it * 256;
        int o = item >> 6, m = item & 63;
        float ar = 0.f, ai = 0.f;
#pragma unroll
        for (int i2 = 0; i2 < 8; ++i2) {
            float xr = X[i2][2 * m], xi = X[i2][2 * m + 1];
            size_t wo = ((size_t)(i2 * 8 + o) * 64 + e) * 64 + m;
            float wrv = wr[wo], wiv = wi[wo];
            ar += xr * wrv - xi * wiv;
            ai += xr * wiv + xi * wrv;
        }
        int row = b * HEsz + o * 64 + e;
        *(unsigned*)(Cf + (size_t)row * 128 + 2 * m) = pk2(ar, -ai);
    }
}

__global__ __launch_bounds__(256, 2) void k_idft(const unsigned short* __restrict__ Cf,
                                                 float* __restrict__ out) {
    __shared__ unsigned short As[128 * 128];
    __shared__ unsigned short Bs[128 * 128];
    const int l0 = blockIdx.x * 128, row0 = blockIdx.y * 128;
    const int t = threadIdx.x, lane = t & 63, w = t >> 6;
    const int wtm = w & 1, wtn = w >> 1;
    const int quad = lane >> 4, lid = lane & 15;
    uint4 a[8];
#pragma unroll
    for (int it = 0; it < 8; ++it) {
        int slot = t + it * 256;
        int r = slot >> 4, cb = slot & 15;
        a[it] = *(const uint4*)(Cf + (size_t)(row0 + r) * 128 + cb * 8);
    }
    {
        int lr = t >> 1, half = t & 1;
        int lg = l0 + lr;
#pragma unroll
        for (int jj = 0; jj < 8; ++jj) {
            unsigned wv[4];
#pragma unroll
            for (int j = 0; j < 4; ++j) {
                int m = half * 32 + jj * 4 + j;
                float s, co; sc(m, lg, &s, &co);
                float wm = (m == 0) ? (1.0f / Lsz) : (2.0f / Lsz);
                wv[j] = pk2(wm * co, wm * s);
            }
            int cb = half * 8 + jj;
            *(uint4*)(Bs + lr * 128 + ((cb ^ (lr & 15)) * 8)) =
                make_uint4(wv[0], wv[1], wv[2], wv[3]);
        }
    }
#pragma unroll
    for (int it = 0; it < 8; ++it) {
        int slot = t + it * 256;
        int r = slot >> 4, cb = slot & 15;
        *(uint4*)(As + r * 128 + ((cb ^ (r & 15)) * 8)) = a[it];
    }
    __syncthreads();
    f32x4 acc[4][4] = {};
#pragma unroll
    for (int kst = 0; kst < 4; ++kst) {
        short8 af[4], bfr[4];
#pragma unroll
        for (int mt = 0; mt < 4; ++mt) {
            int m = wtm * 64 + mt * 16 + lid;
            int cb = (kst * 4 + quad) ^ (m & 15);
            af[mt] = *(short8*)(As + m * 128 + cb * 8);
        }
#pragma unroll
        for (int nt = 0; nt < 4; ++nt) {
            int n = wtn * 64 + nt * 16 + lid;
            int cb = (kst * 4 + quad) ^ (n & 15);
            bfr[nt] = *(short8*)(Bs + n * 128 + cb * 8);
        }
#pragma unroll
        for (int mt = 0; mt < 4; ++mt)
#pragma unroll
            for (int nt = 0; nt < 4; ++nt)
                acc[mt][nt] = __builtin_amdgcn_mfma_f32_16x16x32_bf16(af[mt], bfr[nt], acc[mt][nt], 0, 0, 0);
    }
    __syncthreads();
    float* outb = (float*)As;
#pragma unroll
    for (int mt = 0; mt < 4; ++mt)
#pragma unroll
        for (int nt = 0; nt < 4; ++nt) {
            int col = wtn * 64 + nt * 16 + lid;
            int c4 = col >> 2, cr = col & 3;
#pragma unroll
            for (int r = 0; r < 4; ++r) {
                int row = wtm * 64 + mt * 16 + quad * 4 + r;
                outb[(size_t)row * 128 + ((c4 ^ (row & 7)) << 2) + cr] = acc[mt][nt][r];
            }
        }
    __syncthreads();
#pragma unroll
    for (int it = 0; it < 16; ++it) {
        int slot = t + it * 256;
        int r = slot >> 5, c4 = slot & 31;
        float4 v = *(float4*)(outb + (size_t)r * 128 + ((c4 ^ (r & 7)) << 2));
        *(float4*)(out + (size_t)(row0 + r) * Lsz + l0 + c4 * 4) = v;
    }
}

extern "C" void kernel_launch(void* const* d_in, const int* in_sizes, int n_in,
                              void* d_out, int out_size, void* d_ws, size_t ws_size,
                              hipStream_t stream) {
    const float* q      = (const float*)d_in[0];
    const float* w_real = (const float*)d_in[3];
    const float* w_imag = (const float*)d_in[4];
    float* out = (float*)d_out;
    char* ws = (char*)d_ws;                   // needs ~9 MiB

    unsigned short* Cf  = (unsigned short*)(ws + OFF_CF);
    unsigned short* C1P = (unsigned short*)(ws + OFF_C1P);

    void* args[] = {(void*)&q, (void*)&w_real, (void*)&w_imag,
                    (void*)&C1P, (void*)&Cf, (void*)&out};
    hipError_t e = hipLaunchCooperativeKernel((const void*)k_fused, dim3(512), dim3(256),
                                              args, 0, stream);
    if (e != hipSuccess) {
        // fallback: previous 3-kernel pipeline
        k_dft      <<<dim3(SPLIT, 8, 4), 256, 0, stream>>>(q, C1P);
        k_mixreduce<<<256, 256, 0, stream>>>(C1P, w_real, w_imag, Cf);
        k_idft     <<<dim3(32, 16), 256, 0, stream>>>(Cf, out);
    }
}

// Round 4
// 142.108 us; speedup vs baseline: 1.7868x; 1.7868x over previous
//
#include <hip/hip_runtime.h>

// Problem constants (B,L,H,E,M) = (4,4096,8,64,64)
#define Bsz 4
#define Lsz 4096
#define HEsz 512      // H*E rows per batch
#define SPLIT 8       // split-K for the forward DFT (v3: 16->8, halves C1P traffic)
#define CHN (Lsz / SPLIT / 64)   // 64-l chunks per block = 8

typedef __attribute__((ext_vector_type(8))) short short8;
typedef __attribute__((ext_vector_type(4))) float f32x4;

// workspace byte offsets (total ~5 MiB; ws is 256 MiB)
#define OFF_CF  0u        // ushort[2048][128] mixed coeffs bf16 (512 KB)
#define OFF_C1P (1u<<20)  // ushort[SPLIT][4][512][128] split-K partials bf16 (4 MB)

static __device__ __forceinline__ unsigned short f2bf(float f) {
    union { float f; unsigned u; } v; v.f = f;
    unsigned u = v.u;
    return (unsigned short)((u + 0x7fffu + ((u >> 16) & 1u)) >> 16);   // RNE
}
static __device__ __forceinline__ unsigned pk2(float a, float b) {
    return (unsigned)f2bf(a) | ((unsigned)f2bf(b) << 16);
}
static __device__ __forceinline__ float bf2f(unsigned short u) {
    union { unsigned u; float f; } v; v.u = ((unsigned)u) << 16;
    return v.f;
}
static __device__ __forceinline__ void sc(int m, int l, float* s, float* c) {
    int r = (m * l) & (Lsz - 1);                       // exact mod, L = 4096
    float ang = (float)r * (6.283185307179586f / (float)Lsz);
    __sincosf(ang, s, c);
}

// ---- Stage 1: forward truncated DFT, bf16 MFMA, split-K bf16 partials ----
// C1P[ks][b][he][c] = sum_{l in slice} q[b][l][he] * basF[c][l]
// basF generated in-kernel: c=2m -> cos(2pi m l/L), c=2m+1 -> -sin (rfft e^{-i t})
// grid (SPLIT, 8 he-tiles, 4 b) = 256 blocks; tile 64he x 128c, K-slice 512.
// register-prefetch q one chunk ahead; coalesced uint4 epilogue via LDS restage.
__global__ __launch_bounds__(256, 2) void k_dft(const float* __restrict__ q,
                                                unsigned short* __restrict__ C1P) {
    __shared__ unsigned short As[64 * 64];    // [he][l], XOR-swizzled 8-blocks, 8 KB
    __shared__ unsigned short Bs[128 * 64];   // [c][l],  XOR-swizzled 8-blocks, 16 KB
    const int ks = blockIdx.x, ht = blockIdx.y, b = blockIdx.z;
    const int he0 = ht * 64;
    const int t = threadIdx.x, lane = t & 63, w = t >> 6;
    const int wtm = w & 1, wtn = w >> 1;      // wave tile: 32he x 64c
    const int quad = lane >> 4, lid = lane & 15;
    f32x4 acc[2][4] = {};

    const int kbeg = ks * (Lsz / SPLIT);
    const float* qp0 = q + ((size_t)(b * Lsz + kbeg + w * 16) * HEsz + he0 + lane);

    float f[16], f2[16];
#pragma unroll
    for (int j = 0; j < 16; ++j) f[j] = qp0[(size_t)j * HEsz];   // prologue: ch 0

#pragma unroll
    for (int ch = 0; ch < CHN; ++ch) {
        // A: pack the already-loaded q slice (transpose done by the load pattern)
        {
            uint4 p0 = make_uint4(pk2(f[0], f[1]), pk2(f[2], f[3]), pk2(f[4], f[5]), pk2(f[6], f[7]));
            uint4 p1 = make_uint4(pk2(f[8], f[9]), pk2(f[10], f[11]), pk2(f[12], f[13]), pk2(f[14], f[15]));
            int row = lane;
            int cb0 = (w * 2) ^ (row & 7), cb1 = (w * 2 + 1) ^ (row & 7);
            *(uint4*)(As + row * 64 + cb0 * 8) = p0;
            *(uint4*)(As + row * 64 + cb1 * 8) = p1;
        }
        // prefetch ch+1 q into registers: latency hides under bgen + barrier + MFMA
        if (ch < CHN - 1) {
            const float* qp = qp0 + (size_t)(ch + 1) * 64 * HEsz;
#pragma unroll
            for (int j = 0; j < 16; ++j) f2[j] = qp[(size_t)j * HEsz];
        }
        // B: generate basF tile in-register. thread -> m = t&63, 16 l's.
        {
            int m = t & 63, lg = t >> 6;      // lg in [0,4): l-sub = lg*16..+16
            int c0 = 2 * m, c1 = 2 * m + 1;
            const int l0 = kbeg + ch * 64;
#pragma unroll
            for (int h = 0; h < 2; ++h) {     // two 8-l halves
                float sv[8], cv[8];
#pragma unroll
                for (int j = 0; j < 8; ++j)
                    sc(m, l0 + lg * 16 + h * 8 + j, &sv[j], &cv[j]);
                uint4 pc = make_uint4(pk2(cv[0], cv[1]), pk2(cv[2], cv[3]),
                                      pk2(cv[4], cv[5]), pk2(cv[6], cv[7]));
                uint4 ps = make_uint4(pk2(-sv[0], -sv[1]), pk2(-sv[2], -sv[3]),
                                      pk2(-sv[4], -sv[5]), pk2(-sv[6], -sv[7]));
                int lb = lg * 2 + h;          // l-block index within 64 (8 blocks)
                *(uint4*)(Bs + c0 * 64 + ((lb ^ (c0 & 7)) * 8)) = pc;
                *(uint4*)(Bs + c1 * 64 + ((lb ^ (c1 & 7)) * 8)) = ps;
            }
        }
        __syncthreads();
#pragma unroll
        for (int kst = 0; kst < 2; ++kst) {
            short8 af[2], bfr[4];
#pragma unroll
            for (int mt = 0; mt < 2; ++mt) {
                int m = wtm * 32 + mt * 16 + lid;
                int cb = (kst * 4 + quad) ^ (m & 7);
                af[mt] = *(short8*)(As + m * 64 + cb * 8);
            }
#pragma unroll
            for (int nt = 0; nt < 4; ++nt) {
                int n = wtn * 64 + nt * 16 + lid;
                int cb = (kst * 4 + quad) ^ (n & 7);
                bfr[nt] = *(short8*)(Bs + n * 64 + cb * 8);
            }
#pragma unroll
            for (int mt = 0; mt < 2; ++mt)
#pragma unroll
                for (int nt = 0; nt < 4; ++nt)
                    acc[mt][nt] = __builtin_amdgcn_mfma_f32_16x16x32_bf16(af[mt], bfr[nt], acc[mt][nt], 0, 0, 0);
        }
        __syncthreads();
        if (ch < CHN - 1) {
#pragma unroll
            for (int j = 0; j < 16; ++j) f[j] = f2[j];
        }
    }
    // epilogue: C/D layout col=lane&15, row=quad*4+reg.
    // Stage bf16 result into Bs (16 KB, XOR-swizzled), then coalesced uint4 stores.
#pragma unroll
    for (int mt = 0; mt < 2; ++mt)
#pragma unroll
        for (int nt = 0; nt < 4; ++nt) {
            int col = wtn * 64 + nt * 16 + lid;
#pragma unroll
            for (int r = 0; r < 4; ++r) {
                int row = wtm * 32 + mt * 16 + quad * 4 + r;
                int cb = (col >> 3) ^ (row & 15);
                Bs[row * 128 + cb * 8 + (col & 7)] = f2bf(acc[mt][nt][r]);
            }
        }
    __syncthreads();
    unsigned short* dst = C1P + (((size_t)ks * Bsz + b) * HEsz + he0) * 128;
#pragma unroll
    for (int it = 0; it < 4; ++it) {
        int slot = t + it * 256;              // 1024 slots: r = slot>>4, cb = slot&15
        int r = slot >> 4, cb = slot & 15;
        *(uint4*)(dst + (size_t)r * 128 + cb * 8) =
            *(const uint4*)(Bs + r * 128 + ((cb ^ (r & 15)) * 8));
    }
}

// ---- Stage 2: fused split-K reduce + head mixing, bf16 Cf output ----
// grid (4b * 64e) = 256 blocks. Block reduces X[i=8][c=128] over SPLIT bf16 partials,
// then res[o,m] = sum_i X[i,m] * w[i,o,e,m]; Cf = (Re, -Im) bf16 (1/L weights folded
// into the inverse basis inside k_idft).
__global__ __launch_bounds__(256) void k_mixreduce(const unsigned short* __restrict__ C1P,
                                                   const float* __restrict__ wr,
                                                   const float* __restrict__ wi,
                                                   unsigned short* __restrict__ Cf) {
    __shared__ float X[8][128];
    const int e = blockIdx.x & 63, b = blockIdx.x >> 6;
    const int t = threadIdx.x;
    const int i = t >> 5, c4 = t & 31;        // 4 c's per thread
    size_t off = ((size_t)b * HEsz + i * 64 + e) * 128 + c4 * 4;
    float sx = 0.f, sy = 0.f, sz = 0.f, sw = 0.f;
#pragma unroll
    for (int sp = 0; sp < SPLIT; ++sp) {
        uint2 v = *(const uint2*)(C1P + off + (size_t)sp * (Bsz * HEsz * 128));
        sx += bf2f((unsigned short)(v.x & 0xffff));
        sy += bf2f((unsigned short)(v.x >> 16));
        sz += bf2f((unsigned short)(v.y & 0xffff));
        sw += bf2f((unsigned short)(v.y >> 16));
    }
    *(float4*)&X[i][c4 * 4] = make_float4(sx, sy, sz, sw);
    __syncthreads();
#pragma unroll
    for (int it = 0; it < 2; ++it) {
        int item = t + it * 256;              // 512: o = item>>6, m = item&63
        int o = item >> 6, m = item & 63;
        float ar = 0.f, ai = 0.f;
#pragma unroll
        for (int i2 = 0; i2 < 8; ++i2) {
            float xr = X[i2][2 * m], xi = X[i2][2 * m + 1];
            size_t wo = ((size_t)(i2 * 8 + o) * 64 + e) * 64 + m;
            float wrv = wr[wo], wiv = wi[wo];
            ar += xr * wrv - xi * wiv;
            ai += xr * wiv + xi * wrv;
        }
        int row = b * HEsz + o * 64 + e;
        *(unsigned*)(Cf + (size_t)row * 128 + 2 * m) = pk2(ar, -ai);
    }
}

// ---- Stage 3: truncated irfft, bf16 MFMA, inverse basis generated in-kernel ----
// out[row][l] = sum_k Cf[row][k] * basI[k][l]; basI[2m][l]=wm*cos, [2m+1][l]=wm*sin,
// wm = (m==0?1:2)/L. grid (32 lt, 16 rt), tile 128x128, K=128.
// Cf loads issued FIRST so latency hides under sincos basis generation.
__global__ __launch_bounds__(256, 2) void k_idft(const unsigned short* __restrict__ Cf,
                                                 float* __restrict__ out) {
    __shared__ unsigned short As[128 * 128];  // [row][k] swz16, 32 KB
    __shared__ unsigned short Bs[128 * 128];  // [l][k]  swz16, 32 KB
    const int l0 = blockIdx.x * 128, row0 = blockIdx.y * 128;
    const int t = threadIdx.x, lane = t & 63, w = t >> 6;
    const int wtm = w & 1, wtn = w >> 1;      // wave tile 64 x 64
    const int quad = lane >> 4, lid = lane & 15;
    // A: issue Cf loads to registers (consumed after basis gen)
    uint4 a[8];
#pragma unroll
    for (int it = 0; it < 8; ++it) {
        int slot = t + it * 256;              // 2048: r = slot>>4, cb = slot&15
        int r = slot >> 4, cb = slot & 15;
        a[it] = *(const uint4*)(Cf + (size_t)(row0 + r) * 128 + cb * 8);
    }
    // B: generate basI tile. thread -> l-row = t>>1, half = t&1 (32 m's each).
    {
        int lr = t >> 1, half = t & 1;
        int lg = l0 + lr;
#pragma unroll
        for (int jj = 0; jj < 8; ++jj) {      // 8 k-blocks of 8 (= 4 m's each)
            unsigned wv[4];
#pragma unroll
            for (int j = 0; j < 4; ++j) {
                int m = half * 32 + jj * 4 + j;
                float s, co; sc(m, lg, &s, &co);
                float wm = (m == 0) ? (1.0f / Lsz) : (2.0f / Lsz);
                wv[j] = pk2(wm * co, wm * s);
            }
            int cb = half * 8 + jj;
            *(uint4*)(Bs + lr * 128 + ((cb ^ (lr & 15)) * 8)) =
                make_uint4(wv[0], wv[1], wv[2], wv[3]);
        }
    }
    // A: write staged Cf rows to LDS
#pragma unroll
    for (int it = 0; it < 8; ++it) {
        int slot = t + it * 256;
        int r = slot >> 4, cb = slot & 15;
        *(uint4*)(As + r * 128 + ((cb ^ (r & 15)) * 8)) = a[it];
    }
    __syncthreads();
    f32x4 acc[4][4] = {};
#pragma unroll
    for (int kst = 0; kst < 4; ++kst) {
        short8 af[4], bfr[4];
#pragma unroll
        for (int mt = 0; mt < 4; ++mt) {
            int m = wtm * 64 + mt * 16 + lid;
            int cb = (kst * 4 + quad) ^ (m & 15);
            af[mt] = *(short8*)(As + m * 128 + cb * 8);
        }
#pragma unroll
        for (int nt = 0; nt < 4; ++nt) {
            int n = wtn * 64 + nt * 16 + lid;
            int cb = (kst * 4 + quad) ^ (n & 15);
            bfr[nt] = *(short8*)(Bs + n * 128 + cb * 8);
        }
#pragma unroll
        for (int mt = 0; mt < 4; ++mt)
#pragma unroll
            for (int nt = 0; nt < 4; ++nt)
                acc[mt][nt] = __builtin_amdgcn_mfma_f32_16x16x32_bf16(af[mt], bfr[nt], acc[mt][nt], 0, 0, 0);
    }
    __syncthreads();
    // transpose through LDS (reuse As/Bs as float[128][128]) for float4 stores;
    // XOR-swizzle 4-float blocks by row to kill the 4-way write conflict.
    float* outb = (float*)As;
#pragma unroll
    for (int mt = 0; mt < 4; ++mt)
#pragma unroll
        for (int nt = 0; nt < 4; ++nt) {
            int col = wtn * 64 + nt * 16 + lid;
            int c4 = col >> 2, cr = col & 3;
#pragma unroll
            for (int r = 0; r < 4; ++r) {
                int row = wtm * 64 + mt * 16 + quad * 4 + r;
                outb[(size_t)row * 128 + ((c4 ^ (row & 7)) << 2) + cr] = acc[mt][nt][r];
            }
        }
    __syncthreads();
#pragma unroll
    for (int it = 0; it < 16; ++it) {
        int slot = t + it * 256;              // 4096 float4: r = slot>>5, c4 = slot&31
        int r = slot >> 5, c4 = slot & 31;
        float4 v = *(float4*)(outb + (size_t)r * 128 + ((c4 ^ (r & 7)) << 2));
        *(float4*)(out + (size_t)(row0 + r) * Lsz + l0 + c4 * 4) = v;
    }
}

extern "C" void kernel_launch(void* const* d_in, const int* in_sizes, int n_in,
                              void* d_out, int out_size, void* d_ws, size_t ws_size,
                              hipStream_t stream) {
    const float* q      = (const float*)d_in[0];
    const float* w_real = (const float*)d_in[3];
    const float* w_imag = (const float*)d_in[4];
    float* out = (float*)d_out;
    char* ws = (char*)d_ws;                   // needs ~5 MiB

    unsigned short* Cf  = (unsigned short*)(ws + OFF_CF);
    unsigned short* C1P = (unsigned short*)(ws + OFF_C1P);

    k_dft      <<<dim3(SPLIT, 8, 4), 256, 0, stream>>>(q, C1P);
    k_mixreduce<<<256, 256, 0, stream>>>(C1P, w_real, w_imag, Cf);
    k_idft     <<<dim3(32, 16), 256, 0, stream>>>(Cf, out);
}